// Round 5
// baseline (346.624 us; speedup 1.0000x reference)
//
#include <hip/hip_runtime.h>
#include <hip/hip_bf16.h>

typedef __bf16 bf16x8 __attribute__((ext_vector_type(8)));
typedef __bf16 bf16x4 __attribute__((ext_vector_type(4)));
typedef float  f32x4  __attribute__((ext_vector_type(4)));

#define HL   50     // history length
#define DD   64     // embed dim
#define NPB  2      // nodes per pair-iteration
#define ITER 4      // pairs per block (weights amortized, gathers pipelined)
#define MR   112    // padded M rows (100 live + 12 garbage)
#define MT   7      // M tiles
#define XSS  136    // xs row stride bf16

// Software-pipelined 4-pair block:
//   loop-top: drain prefetched gathers (regs) -> xs(bf16)      [stall mostly hidden]
//   barrier[1]; issue prefetch group A (7 chunks) for pair+1   [hidden by GEMM1]
//   bias-MFMA -> GEMM1(K=128) -> barrier[2] -> h1 -> barrier[3]
//   GEMM2 -> scores -> barrier[4]; issue group B + rep for pair+1 [hidden by tail]
//   softmax -> weighted e_va sum -> partials in garbage rows 100..103
//   barrier[5]; out-write (rows 100..103 only; disjoint from next stores)
// Weight fragments (96 VMEM/thread) loaded ONCE per block = per 8 nodes.
__global__ __launch_bounds__(256, 4) void va_agg_kernel(
    const int*   __restrict__ nodes,
    const int*   __restrict__ hva,
    const int*   __restrict__ haf,
    const float* __restrict__ v2e,
    const float* __restrict__ a2e,
    const float* __restrict__ f2e,
    const float* __restrict__ W1,
    const float* __restrict__ b1,
    const float* __restrict__ W2,
    const float* __restrict__ b2,
    const float* __restrict__ w3,
    float*       __restrict__ out)
{
    __shared__ __bf16 xs[MR * XSS];   // 30464 B: [row][e_va | e_af->h1]
    __shared__ float  pbuf[4 * MR];   // 1792 B : per-wave score partials

    const int tid  = threadIdx.x;
    const int w    = tid >> 6;
    const int lane = tid & 63;
    const int lq   = lane & 15;
    const int quad = lane >> 4;
    const int col  = w * 16 + lq;
    const int pairBase = blockIdx.x * ITER;

    float4 pfa[7];   // prefetch group A: chunks 0..6 (always valid)
    float4 pfb[6];   // prefetch group B: chunks 7..12 (12 valid iff tid<128)
    float4 rr[4];    // rep rows raw (lanes lq<2)

    auto prefA = [&](int pair) {
        const int n0 = pair * NPB;
        const int* hb = hva + n0 * HL;
        const int* fb = haf + n0 * HL;
        #pragma unroll
        for (int i = 0; i < 7; ++i) {
            int t = i * 256 + tid, r = t >> 4, q = t & 15;
            bool va = (r < NPB * HL);
            int gr = va ? r : r - NPB * HL;
            int idx = va ? hb[gr] : fb[gr];
            pfa[i] = *(const float4*)((va ? a2e : f2e) + (size_t)idx * DD + q * 4);
        }
    };
    auto prefB = [&](int pair) {
        const int n0 = pair * NPB;
        const int* hb = hva + n0 * HL;
        const int* fb = haf + n0 * HL;
        #pragma unroll
        for (int i = 0; i < 6; ++i) {
            int t = (i + 7) * 256 + tid;
            if (t < NPB * HL * 2 * 16) {
                int r = t >> 4, q = t & 15;
                bool va = (r < NPB * HL);
                int gr = va ? r : r - NPB * HL;
                int idx = va ? hb[gr] : fb[gr];
                pfb[i] = *(const float4*)((va ? a2e : f2e) + (size_t)idx * DD + q * 4);
            }
        }
        if (lq < NPB) {
            int nd = nodes[n0 + lq];
            const float* rp = v2e + (size_t)nd * DD;
            rr[0] = *(const float4*)(rp + quad * 8);
            rr[1] = *(const float4*)(rp + quad * 8 + 4);
            rr[2] = *(const float4*)(rp + 32 + quad * 8);
            rr[3] = *(const float4*)(rp + 32 + quad * 8 + 4);
        }
    };
    auto storeAll = [&]() {
        #pragma unroll
        for (int i = 0; i < 7; ++i) {
            int t = i * 256 + tid, r = t >> 4, q = t & 15;
            bool va = (r < NPB * HL);
            int gr = va ? r : r - NPB * HL;
            float4 v = pfa[i];
            bf16x4 pk = {(__bf16)v.x, (__bf16)v.y, (__bf16)v.z, (__bf16)v.w};
            *(bf16x4*)&xs[gr * XSS + (va ? 0 : DD) + q * 4] = pk;
        }
        #pragma unroll
        for (int i = 0; i < 6; ++i) {
            int t = (i + 7) * 256 + tid;
            if (t < NPB * HL * 2 * 16) {
                int r = t >> 4, q = t & 15;
                bool va = (r < NPB * HL);
                int gr = va ? r : r - NPB * HL;
                float4 v = pfb[i];
                bf16x4 pk = {(__bf16)v.x, (__bf16)v.y, (__bf16)v.z, (__bf16)v.w};
                *(bf16x4*)&xs[gr * XSS + (va ? 0 : DD) + q * 4] = pk;
            }
        }
    };

    // ---- issue pair-0 prefetch FIRST (longest latency), then weights ----
    prefA(pairBase);
    prefB(pairBase);

    // ---- weight fragments, ONCE per block (B-layout: B[k=quad*8+j][lq]) ----
    bf16x8 b1f[4], b1u[2], b2f[2];
    #pragma unroll
    for (int t = 0; t < 4; ++t)
        #pragma unroll
        for (int j = 0; j < 8; ++j) {
            int keff = t * 32 + quad * 8 + j;
            int krow = (keff < 64) ? keff : keff + 64;
            b1f[t][j] = (__bf16)W1[krow * 64 + col];
        }
    #pragma unroll
    for (int t = 0; t < 2; ++t)
        #pragma unroll
        for (int j = 0; j < 8; ++j) {
            b1u[t][j] = (__bf16)W1[(64 + t * 32 + quad * 8 + j) * 64 + col];
            b2f[t][j] = (__bf16)W2[(t * 32 + quad * 8 + j) * 64 + col];
        }
    const float w3c = w3[col];
    const float b1c = b1[col];
    const float b2c = b2[col];

    for (int it = 0; it < ITER; ++it) {
        // ---- drain prefetch into xs; build rep A-fragment ----
        storeAll();
        bf16x8 repf[2];
        #pragma unroll
        for (int t = 0; t < 2; ++t) {
            float4 v0 = rr[2 * t], v1 = rr[2 * t + 1];
            repf[t] = (bf16x8){(__bf16)v0.x, (__bf16)v0.y, (__bf16)v0.z, (__bf16)v0.w,
                               (__bf16)v1.x, (__bf16)v1.y, (__bf16)v1.z, (__bf16)v1.w};
        }
        if (lq >= NPB)
            #pragma unroll
            for (int t = 0; t < 2; ++t)
                #pragma unroll
                for (int j = 0; j < 8; ++j) repf[t][j] = (__bf16)0.f;
        __syncthreads();   // [1] xs visible

        if (it + 1 < ITER) prefA(pairBase + it + 1);   // hidden by GEMM1

        // ---- bias MFMA: rows 0,1 = rep_n . W1[64:128, col] ----
        f32x4 rb = {0.f, 0.f, 0.f, 0.f};
        #pragma unroll
        for (int t = 0; t < 2; ++t)
            rb = __builtin_amdgcn_mfma_f32_16x16x32_bf16(repf[t], b1u[t], rb, 0, 0, 0);
        const float bias0 = __shfl(rb[0], lq) + b1c;
        const float bias1 = __shfl(rb[1], lq) + b1c;

        // ---- GEMM1: h1 = relu(x @ W1eff + bias), M=112, K=128 ----
        f32x4 acc[MT];
        #pragma unroll
        for (int mt = 0; mt < MT; ++mt)
            #pragma unroll
            for (int r = 0; r < 4; ++r) {
                int gr = mt * 16 + quad * 4 + r;
                acc[mt][r] = (gr >= HL) ? bias1 : bias0;
            }
        #pragma unroll
        for (int t = 0; t < 4; ++t)
            #pragma unroll
            for (int mt = 0; mt < MT; ++mt) {
                bf16x8 a = *(const bf16x8*)&xs[(mt * 16 + lq) * XSS + t * 32 + quad * 8];
                acc[mt] = __builtin_amdgcn_mfma_f32_16x16x32_bf16(a, b1f[t], acc[mt], 0, 0, 0);
            }
        __syncthreads();   // [2] e_af reads done before overwrite
        #pragma unroll
        for (int mt = 0; mt < MT; ++mt)
            #pragma unroll
            for (int r = 0; r < 4; ++r) {
                int gr = mt * 16 + quad * 4 + r;
                xs[gr * XSS + DD + col] = (__bf16)fmaxf(acc[mt][r], 0.f);
            }
        __syncthreads();   // [3] h1 visible

        // ---- GEMM2 + scores ----
        f32x4 a2[MT];
        #pragma unroll
        for (int mt = 0; mt < MT; ++mt) a2[mt] = (f32x4){b2c, b2c, b2c, b2c};
        #pragma unroll
        for (int t = 0; t < 2; ++t)
            #pragma unroll
            for (int mt = 0; mt < MT; ++mt) {
                bf16x8 a = *(const bf16x8*)&xs[(mt * 16 + lq) * XSS + DD + t * 32 + quad * 8];
                a2[mt] = __builtin_amdgcn_mfma_f32_16x16x32_bf16(a, b2f[t], a2[mt], 0, 0, 0);
            }
        #pragma unroll
        for (int mt = 0; mt < MT; ++mt) {
            float p0 = fmaxf(a2[mt][0], 0.f) * w3c;
            float p1 = fmaxf(a2[mt][1], 0.f) * w3c;
            float p2 = fmaxf(a2[mt][2], 0.f) * w3c;
            float p3 = fmaxf(a2[mt][3], 0.f) * w3c;
            #pragma unroll
            for (int m = 1; m < 16; m <<= 1) {
                p0 += __shfl_xor(p0, m);
                p1 += __shfl_xor(p1, m);
                p2 += __shfl_xor(p2, m);
                p3 += __shfl_xor(p3, m);
            }
            if (lq == 0) {
                int rowb = mt * 16 + quad * 4;
                pbuf[w * MR + rowb + 0] = p0;
                pbuf[w * MR + rowb + 1] = p1;
                pbuf[w * MR + rowb + 2] = p2;
                pbuf[w * MR + rowb + 3] = p3;
            }
        }
        __syncthreads();   // [4] scores visible

        if (it + 1 < ITER) prefB(pairBase + it + 1);   // hidden by softmax/sum

        // ---- redundant per-wave softmax (node = w&1); b3 cancels ----
        const int n  = w & 1;
        const int lh = w >> 1;
        float att;
        {
            float s = -3.0e38f;
            if (lane < HL) {
                int gr = n * HL + lane;
                s = pbuf[gr] + pbuf[MR + gr] + pbuf[2 * MR + gr] + pbuf[3 * MR + gr];
            }
            float mx = s;
            #pragma unroll
            for (int m = 1; m < 64; m <<= 1) mx = fmaxf(mx, __shfl_xor(mx, m));
            float e = (lane < HL) ? __expf(s - mx) : 0.f;
            float sm = e;
            #pragma unroll
            for (int m = 1; m < 64; m <<= 1) sm += __shfl_xor(sm, m);
            att = e / sm;
        }

        // ---- weighted e_va sum; partials into garbage rows 100..103 ----
        {
            float o = 0.f;
            const int lb = lh * 25;
            #pragma unroll
            for (int i = 0; i < 25; ++i) {
                int l = lb + i;
                float av = __shfl(att, l);
                o = fmaf(av, (float)xs[(n * HL + l) * XSS + lane], o);
            }
            float* op = (float*)&xs[(100 + w) * XSS + DD];
            op[lane] = o;
        }
        __syncthreads();   // [5] partials visible; also fences next xs stores
        if (w < NPB) {
            const float* p0 = (const float*)&xs[(100 + w) * XSS + DD];
            const float* p1 = (const float*)&xs[(100 + w + 2) * XSS + DD];
            out[(size_t)((pairBase + it) * NPB + w) * DD + lane] = p0[lane] + p1[lane];
        }
    }
}

extern "C" void kernel_launch(void* const* d_in, const int* in_sizes, int n_in,
                              void* d_out, int out_size, void* d_ws, size_t ws_size,
                              hipStream_t stream) {
    const int*   nodes = (const int*)d_in[0];
    const int*   hva   = (const int*)d_in[1];
    const int*   haf   = (const int*)d_in[2];
    const float* v2e   = (const float*)d_in[3];
    const float* a2e   = (const float*)d_in[4];
    const float* f2e   = (const float*)d_in[5];
    const float* W1    = (const float*)d_in[6];
    const float* b1    = (const float*)d_in[7];
    const float* W2    = (const float*)d_in[8];
    const float* b2    = (const float*)d_in[9];
    const float* w3    = (const float*)d_in[10];
    // d_in[11] = b3: softmax shift-invariant — unused.
    float* out = (float*)d_out;

    const int N = in_sizes[0];                 // 8192
    const int blocks = N / (NPB * ITER);       // 1024 = 4 blocks/CU
    va_agg_kernel<<<blocks, 256, 0, stream>>>(nodes, hva, haf, v2e, a2e, f2e,
                                              W1, b1, W2, b2, w3, out);
}

// Round 6
// 167.533 us; speedup vs baseline: 2.0690x; 2.0690x over previous
//
#include <hip/hip_runtime.h>
#include <hip/hip_bf16.h>

typedef __bf16 bf16x8 __attribute__((ext_vector_type(8)));
typedef __bf16 bf16x4 __attribute__((ext_vector_type(4)));
typedef float  f32x4  __attribute__((ext_vector_type(4)));

#define HL   50     // history length
#define DD   64     // embed dim
#define NPB  2      // nodes per block
#define MR   112    // padded M rows (100 live + 12 garbage)
#define MT   7      // M tiles
#define XSS  136    // xs row stride bf16

// ws layout: [0, 32768): 256 fragment-sets (fid = quad*64+col), each 64 bf16 =
//   { b1f[0..3] | b1u[0..1] | b2f[0..1] } x 8 bf16, built by va_prep_kernel in
//   exact mfma B-fragment order (lane holds B[k=quad*8+j][col]).
// [32768, 33536): f32 scalars { w3[64] | b1[64] | b2[64] }.
__global__ __launch_bounds__(256) void va_prep_kernel(
    const float* __restrict__ W1, const float* __restrict__ W2,
    const float* __restrict__ w3, const float* __restrict__ b1,
    const float* __restrict__ b2,
    __bf16* __restrict__ wf, float* __restrict__ wsc)
{
    const int tid  = threadIdx.x;     // fid 0..255
    const int quad = tid >> 6;
    const int col  = tid & 63;
    __bf16* dst = wf + tid * 64;
    #pragma unroll
    for (int t = 0; t < 4; ++t)
        #pragma unroll
        for (int j = 0; j < 8; ++j) {
            int keff = t * 32 + quad * 8 + j;           // x-col 0..127
            int krow = (keff < 64) ? keff : keff + 64;  // W1 rows 0-63 / 128-191
            dst[t * 8 + j] = (__bf16)W1[krow * 64 + col];
        }
    #pragma unroll
    for (int t = 0; t < 2; ++t)
        #pragma unroll
        for (int j = 0; j < 8; ++j) {
            dst[32 + t * 8 + j] = (__bf16)W1[(64 + t * 32 + quad * 8 + j) * 64 + col];
            dst[48 + t * 8 + j] = (__bf16)W2[(t * 32 + quad * 8 + j) * 64 + col];
        }
    if (tid < 64) {
        wsc[tid]       = w3[tid];
        wsc[64 + tid]  = b1[tid];
        wsc[128 + tid] = b2[tid];
    }
}

// R4 structure (proven 81 us) with weight-fragment build replaced by
// 8x dwordx4 loads from the prep-packed ws (saves ~250 VALU + ~59 VMEM
// per thread vs scalar-load+pack). Everything else identical to R4.
__global__ __launch_bounds__(256, 5) void va_agg_kernel(
    const int*    __restrict__ nodes,
    const int*    __restrict__ hva,
    const int*    __restrict__ haf,
    const float*  __restrict__ v2e,
    const float*  __restrict__ a2e,
    const float*  __restrict__ f2e,
    const __bf16* __restrict__ wf,
    const float*  __restrict__ wsc,
    float*        __restrict__ out)
{
    __shared__ __bf16 xs[MR * XSS];   // 30464 B: [row][e_va | e_af->h1]
    __shared__ float  pbuf[4 * MR];   // 1792 B : per-wave score partials

    const int tid  = threadIdx.x;
    const int w    = tid >> 6;
    const int lane = tid & 63;
    const int lq   = lane & 15;
    const int quad = lane >> 4;
    const int col  = w * 16 + lq;
    const int n0   = blockIdx.x * NPB;

    // ---- gathers FIRST: 200 rows x 16 float4 chunks (independent VMEM) ----
    {
        const int* hb = hva + n0 * HL;
        const int* fb = haf + n0 * HL;
        #pragma unroll
        for (int i = 0; i < 13; ++i) {
            int t = i * 256 + tid;
            if (t < NPB * HL * 2 * 16) {
                int r = t >> 4, q = t & 15;
                bool va = (r < NPB * HL);
                int gr = va ? r : r - NPB * HL;
                int idx = va ? hb[gr] : fb[gr];
                const float* src = (va ? a2e : f2e) + (size_t)idx * DD + q * 4;
                float4 v = *(const float4*)src;
                bf16x4 pk = {(__bf16)v.x, (__bf16)v.y, (__bf16)v.z, (__bf16)v.w};
                *(bf16x4*)&xs[gr * XSS + (va ? 0 : DD) + q * 4] = pk;
            }
        }
    }

    // ---- rep A-fragment direct from global (lanes lq<2 = the 2 nodes) ----
    bf16x8 repf[2];
    #pragma unroll
    for (int t = 0; t < 2; ++t)
        #pragma unroll
        for (int j = 0; j < 8; ++j) repf[t][j] = (__bf16)0.f;
    if (lq < NPB) {
        int nd = nodes[n0 + lq];
        const float* rp = v2e + (size_t)nd * DD;
        #pragma unroll
        for (int t = 0; t < 2; ++t) {
            float4 v0 = *(const float4*)(rp + t * 32 + quad * 8);
            float4 v1 = *(const float4*)(rp + t * 32 + quad * 8 + 4);
            repf[t] = (bf16x8){(__bf16)v0.x, (__bf16)v0.y, (__bf16)v0.z, (__bf16)v0.w,
                               (__bf16)v1.x, (__bf16)v1.y, (__bf16)v1.z, (__bf16)v1.w};
        }
    }

    // ---- weight fragments: straight vector loads from prep-packed ws ----
    const __bf16* fbp = wf + (size_t)(quad * 64 + col) * 64;
    bf16x8 b1f[4], b1u[2], b2f[2];
    #pragma unroll
    for (int t = 0; t < 4; ++t) b1f[t] = *(const bf16x8*)(fbp + t * 8);
    #pragma unroll
    for (int t = 0; t < 2; ++t) {
        b1u[t] = *(const bf16x8*)(fbp + 32 + t * 8);
        b2f[t] = *(const bf16x8*)(fbp + 48 + t * 8);
    }
    const float w3c = wsc[col];
    const float b1c = wsc[64 + col];
    const float b2c = wsc[128 + col];

    // ---- bias MFMA (per-wave, no LDS): rows 0,1 = rep_n . W1[64:128, col] ----
    f32x4 rb = {0.f, 0.f, 0.f, 0.f};
    #pragma unroll
    for (int t = 0; t < 2; ++t)
        rb = __builtin_amdgcn_mfma_f32_16x16x32_bf16(repf[t], b1u[t], rb, 0, 0, 0);
    const float bias0 = __shfl(rb[0], lq) + b1c;
    const float bias1 = __shfl(rb[1], lq) + b1c;

    __syncthreads();   // [1] gathers visible

    // ---- GEMM1: h1 = relu(x @ W1eff + bias), M=112, K=128 ----
    f32x4 acc[MT];
    #pragma unroll
    for (int mt = 0; mt < MT; ++mt)
        #pragma unroll
        for (int r = 0; r < 4; ++r) {
            int gr = mt * 16 + quad * 4 + r;
            acc[mt][r] = (gr >= HL) ? bias1 : bias0;
        }
    #pragma unroll
    for (int t = 0; t < 4; ++t)
        #pragma unroll
        for (int mt = 0; mt < MT; ++mt) {
            bf16x8 a = *(const bf16x8*)&xs[(mt * 16 + lq) * XSS + t * 32 + quad * 8];
            acc[mt] = __builtin_amdgcn_mfma_f32_16x16x32_bf16(a, b1f[t], acc[mt], 0, 0, 0);
        }
    __syncthreads();   // [2] e_af reads done before overwrite
    #pragma unroll
    for (int mt = 0; mt < MT; ++mt)
        #pragma unroll
        for (int r = 0; r < 4; ++r) {
            int gr = mt * 16 + quad * 4 + r;
            xs[gr * XSS + DD + col] = (__bf16)fmaxf(acc[mt][r], 0.f);
        }
    __syncthreads();   // [3] h1 visible

    // ---- GEMM2 + scores ----
    f32x4 a2[MT];
    #pragma unroll
    for (int mt = 0; mt < MT; ++mt) a2[mt] = (f32x4){b2c, b2c, b2c, b2c};
    #pragma unroll
    for (int t = 0; t < 2; ++t)
        #pragma unroll
        for (int mt = 0; mt < MT; ++mt) {
            bf16x8 a = *(const bf16x8*)&xs[(mt * 16 + lq) * XSS + DD + t * 32 + quad * 8];
            a2[mt] = __builtin_amdgcn_mfma_f32_16x16x32_bf16(a, b2f[t], a2[mt], 0, 0, 0);
        }
    #pragma unroll
    for (int mt = 0; mt < MT; ++mt) {
        float p0 = fmaxf(a2[mt][0], 0.f) * w3c;
        float p1 = fmaxf(a2[mt][1], 0.f) * w3c;
        float p2 = fmaxf(a2[mt][2], 0.f) * w3c;
        float p3 = fmaxf(a2[mt][3], 0.f) * w3c;
        #pragma unroll
        for (int m = 1; m < 16; m <<= 1) {
            p0 += __shfl_xor(p0, m);
            p1 += __shfl_xor(p1, m);
            p2 += __shfl_xor(p2, m);
            p3 += __shfl_xor(p3, m);
        }
        if (lq == 0) {
            int rowb = mt * 16 + quad * 4;
            pbuf[w * MR + rowb + 0] = p0;
            pbuf[w * MR + rowb + 1] = p1;
            pbuf[w * MR + rowb + 2] = p2;
            pbuf[w * MR + rowb + 3] = p3;
        }
    }
    __syncthreads();   // [4] scores visible

    // ---- redundant per-wave softmax (node = w&1); b3 cancels ----
    const int n  = w & 1;
    const int lh = w >> 1;
    float att;
    {
        float s = -3.0e38f;
        if (lane < HL) {
            int gr = n * HL + lane;
            s = pbuf[gr] + pbuf[MR + gr] + pbuf[2 * MR + gr] + pbuf[3 * MR + gr];
        }
        float mx = s;
        #pragma unroll
        for (int m = 1; m < 64; m <<= 1) mx = fmaxf(mx, __shfl_xor(mx, m));
        float e = (lane < HL) ? __expf(s - mx) : 0.f;
        float sm = e;
        #pragma unroll
        for (int m = 1; m < 64; m <<= 1) sm += __shfl_xor(sm, m);
        att = e / sm;
    }

    // ---- weighted e_va sum; partials into h1-half of GARBAGE rows 100-103 ----
    {
        float o = 0.f;
        const int lb = lh * 25;
        #pragma unroll
        for (int i = 0; i < 25; ++i) {
            int l = lb + i;
            float av = __shfl(att, l);
            o = fmaf(av, (float)xs[(n * HL + l) * XSS + lane], o);
        }
        float* op = (float*)&xs[(100 + w) * XSS + DD];  // dead rows; spill also dead
        op[lane] = o;
    }
    __syncthreads();   // [5] partials visible
    if (w < NPB) {
        const float* p0 = (const float*)&xs[(100 + w) * XSS + DD];
        const float* p1 = (const float*)&xs[(100 + w + 2) * XSS + DD];
        out[(size_t)(n0 + w) * DD + lane] = p0[lane] + p1[lane];
    }
}

extern "C" void kernel_launch(void* const* d_in, const int* in_sizes, int n_in,
                              void* d_out, int out_size, void* d_ws, size_t ws_size,
                              hipStream_t stream) {
    const int*   nodes = (const int*)d_in[0];
    const int*   hva   = (const int*)d_in[1];
    const int*   haf   = (const int*)d_in[2];
    const float* v2e   = (const float*)d_in[3];
    const float* a2e   = (const float*)d_in[4];
    const float* f2e   = (const float*)d_in[5];
    const float* W1    = (const float*)d_in[6];
    const float* b1    = (const float*)d_in[7];
    const float* W2    = (const float*)d_in[8];
    const float* b2    = (const float*)d_in[9];
    const float* w3    = (const float*)d_in[10];
    // d_in[11] = b3: softmax shift-invariant — unused.
    float* out = (float*)d_out;

    __bf16* wf  = (__bf16*)d_ws;                        // 32768 B fragments
    float*  wsc = (float*)((char*)d_ws + 256 * 64 * 2); // 768 B scalars

    va_prep_kernel<<<1, 256, 0, stream>>>(W1, W2, w3, b1, b2, wf, wsc);

    const int N = in_sizes[0];            // 8192
    const int blocks = N / NPB;           // 4096
    va_agg_kernel<<<blocks, 256, 0, stream>>>(nodes, hva, haf, v2e, a2e, f2e,
                                              wf, wsc, out);
}